// Round 17
// baseline (3331.963 us; speedup 1.0000x reference)
//
#include <hip/hip_runtime.h>
#include <stdint.h>

typedef unsigned short ushort_t;
typedef __bf16 bf16x8 __attribute__((ext_vector_type(8)));
typedef ushort_t us8 __attribute__((ext_vector_type(8)));
typedef float f32x4 __attribute__((ext_vector_type(4)));

// ---------- bf16 <-> f32 (bit ops) ----------
__device__ __forceinline__ float b2f(ushort_t u) {
  union { unsigned u; float f; } v; v.u = ((unsigned)u) << 16; return v.f;
}
__device__ __forceinline__ ushort_t f2b(float f) {
  union { float f; unsigned u; } v; v.f = f;
  unsigned r = (v.u + 0x7FFFu + ((v.u >> 16) & 1u)) >> 16;
  return (ushort_t)r;
}

// ---------- fast transcendentals ----------
__device__ __forceinline__ float sigm(float x)     { return 1.f / (1.f + __expf(-x)); }
__device__ __forceinline__ float tanhfast(float x) { return 1.f - 2.f / (1.f + __expf(2.f * x)); }

// ---------- device-coherent write-through stores ----------
__device__ __forceinline__ void store_short_wt(ushort_t* p, ushort_t v) {
  asm volatile("global_store_short %0, %1, off sc0 sc1"
               :: "v"(p), "v"((unsigned)v) : "memory");
}
__device__ __forceinline__ void store_uint_wt(unsigned* p, unsigned v) {
  asm volatile("global_store_dword %0, %1, off sc0 sc1"
               :: "v"(p), "v"(v) : "memory");
}

// ---------- global -> LDS direct load, 16B per lane ----------
__device__ __forceinline__ void gload_lds16(const void* g, void* lds) {
  auto l3 = reinterpret_cast<__attribute__((address_space(3))) unsigned*>(
      reinterpret_cast<uintptr_t>(lds));
  __builtin_amdgcn_global_load_lds(reinterpret_cast<const unsigned*>(g), l3, 16, 0, 0);
}

// raw barrier with compiler memory fences (no vmcnt(0) drain)
__device__ __forceinline__ void rbar() {
  asm volatile("" ::: "memory");
  __builtin_amdgcn_s_barrier();
  asm volatile("" ::: "memory");
}

// =====================================================================
// 256x256 pipelined GEMM, BK=32, double-buffered 64KB STATIC LDS ->
// 2 blocks/CU (inter-block latency hiding) + counted vmcnt(4), raw
// barriers, 2-way-max LDS swizzle (co = (hi ^ ((lrow>>1)&3))*8, both
// sides), setprio. 512 thr = 8 waves (2Mx4N), wave tile 128x64.
// Requires: M%256==0, B rows padded to gridDim.y*256, Kpad%32==0, nt>=2.
// =====================================================================
template <bool F32OUT>
__global__ __launch_bounds__(512) void gemm256(
    const ushort_t* __restrict__ A, const ushort_t* __restrict__ B,
    void* __restrict__ Cv,
    const float* __restrict__ bias0, const float* __restrict__ bias1,
    int lda, int ldb, long ldc, int Kpad, int N)
{
  __shared__ alignas(16) ushort_t sh[2][16384];   // [buf][A 8192 | B 8192]
  const int tid = threadIdx.x;
  const int w = tid >> 6, l = tid & 63;
  const int wr = w >> 2, wc = w & 3;
  const int lrow = l & 15, hi = l >> 4;
  const int co = (hi ^ ((lrow >> 1) & 3)) * 8;   // swizzled read col (elems)

  // bijective XCD swizzle
  unsigned nwg = gridDim.x * gridDim.y;
  unsigned wg = blockIdx.y * gridDim.x + blockIdx.x;
  {
    unsigned q = nwg >> 3, r = nwg & 7u;
    unsigned xcd = wg & 7u, idx = wg >> 3;
    wg = (xcd < r ? xcd * (q + 1) : r * (q + 1) + (xcd - r) * q) + idx;
  }
  const long m0 = (long)(wg % gridDim.x) * 256;
  const long n0 = (long)(wg / gridDim.x) * 256;

  // staging: per tensor 1024 chunks of 8 ushorts; thread does 2 (tid, tid+512).
  // linear LDS dest; global source col inverse-swizzled (same involution).
  int crow[2], csrc[2];
#pragma unroll
  for (int j = 0; j < 2; ++j) {
    int c = tid + j * 512;
    crow[j] = c >> 2;
    csrc[j] = (((c & 3) ^ ((crow[j] >> 1) & 3))) * 8;
  }

  auto STAGE = [&](int buf, int t) {
    const long k0 = (long)t * 32;
    ushort_t* dstA = sh[buf];
    ushort_t* dstB = dstA + 8192;
#pragma unroll
    for (int j = 0; j < 2; ++j)
      gload_lds16(A + (m0 + crow[j]) * lda + k0 + csrc[j], dstA + (tid + j * 512) * 8);
#pragma unroll
    for (int j = 0; j < 2; ++j)
      gload_lds16(B + (n0 + crow[j]) * ldb + k0 + csrc[j], dstB + (tid + j * 512) * 8);
  };

  f32x4 acc[8][4] = {};
  const int nt = Kpad >> 5;

  STAGE(0, 0);
  STAGE(1, 1);
  asm volatile("s_waitcnt vmcnt(4)" ::: "memory");   // tile 0 landed (tile 1 flying)
  rbar();

  for (int t = 0; t < nt; ++t) {
    const ushort_t* As = sh[t & 1];
    const ushort_t* Bs = As + 8192;
    bf16x8 af[8], bfr[4];
#pragma unroll
    for (int mi = 0; mi < 8; ++mi)
      af[mi] = *(const bf16x8*)(As + (wr * 128 + mi * 16 + lrow) * 32 + co);
#pragma unroll
    for (int ni = 0; ni < 4; ++ni)
      bfr[ni] = *(const bf16x8*)(Bs + (wc * 64 + ni * 16 + lrow) * 32 + co);
    __builtin_amdgcn_s_setprio(1);
#pragma unroll
    for (int mi = 0; mi < 8; ++mi)
#pragma unroll
      for (int ni = 0; ni < 4; ++ni)
        acc[mi][ni] = __builtin_amdgcn_mfma_f32_16x16x32_bf16(af[mi], bfr[ni], acc[mi][ni], 0, 0, 0);
    __builtin_amdgcn_s_setprio(0);

    if (t + 2 < nt) {
      rbar();                       // all waves done reading buf[t&1]
      STAGE(t & 1, t + 2);          // 4 loads into the freed buffer
      asm volatile("s_waitcnt vmcnt(4)" ::: "memory");  // tile t+1 landed
      rbar();
    } else if (t + 1 < nt) {
      rbar();
      asm volatile("s_waitcnt vmcnt(0)" ::: "memory");
      rbar();
    }
  }

  // epilogue (r12-proven layout): lane -> col = lrow, rows = hi*4 + r
  const int rbase = hi * 4;
#pragma unroll
  for (int ni = 0; ni < 4; ni++) {
    int gcol = (int)n0 + wc * 64 + ni * 16 + lrow;
    if (gcol < N) {
      float badd = 0.f;
      if (bias0) badd += bias0[gcol];
      if (bias1) badd += bias1[gcol];
#pragma unroll
      for (int mi = 0; mi < 8; mi++) {
#pragma unroll
        for (int r = 0; r < 4; r++) {
          long grow = m0 + wr * 128 + mi * 16 + rbase + r;
          float v = acc[mi][ni][r] + badd;
          if (F32OUT) ((float*)Cv)[grow * ldc + gcol] = v;
          else        ((ushort_t*)Cv)[grow * ldc + gcol] = f2b(v);
        }
      }
    }
  }
}

// =====================================================================
// Persistent LSTM layer (r16 form)
// =====================================================================
__global__ __launch_bounds__(256) void lstm_layer(
    ushort_t* __restrict__ hs,        // [101][64][1152] bf16
    const ushort_t* __restrict__ G,   // [6400][4608] bf16
    const ushort_t* __restrict__ Whh, // padded [4608][1152] bf16
    const float* __restrict__ c_in,   // [64][1150] f32
    unsigned* __restrict__ flags)     // 72 lines of 128B
{
  extern __shared__ ushort_t Bsh[];
  const int tid = threadIdx.x;
  const int w = tid >> 6, l = tid & 63;
  const int us = blockIdx.x;
  const int lrow = l & 15, hi = l >> 4, lk = hi * 8;
  const int u = us * 16 + lrow;
  const int usafe = (u < 1150) ? u : 0;
  const int row0 = w * 16 + hi * 4;
  const int x7 = lrow & 7;
  const int start = us >> 1;

  for (int ci = tid; ci < 9216; ci += 256) {
    int gate = ci / 2304;
    int rem  = ci - gate * 2304;
    int row  = rem / 144;
    int c    = rem - row * 144;
    bf16x8 v = *(const bf16x8*)(Whh + ((long)(gate * 1150 + us * 16 + row)) * 1152 + c * 8);
    *(bf16x8*)(Bsh + (((gate * 16 + row) * 144) + (c ^ (row & 7))) * 8) = v;
  }
  const ushort_t* Bg0 = Bsh + ((0 * 16 + lrow) * 144) * 8;
  const ushort_t* Bg1 = Bsh + ((1 * 16 + lrow) * 144) * 8;
  const ushort_t* Bg2 = Bsh + ((2 * 16 + lrow) * 144) * 8;
  const ushort_t* Bg3 = Bsh + ((3 * 16 + lrow) * 144) * 8;

  f32x4 cc = {};
  if (u < 1150) {
#pragma unroll
    for (int r = 0; r < 4; ++r) cc[r] = c_in[(row0 + r) * 1150 + u];
  }
  __syncthreads();

  const int s1 = l, s2 = 64 + (l & 7);

  for (int t = 0; t < 100; ++t) {
    ushort_t gvv[16];
    {
      const ushort_t* gp = G + ((long)t * 64 + row0) * 4608 + usafe;
#pragma unroll
      for (int r = 0; r < 4; ++r)
#pragma unroll
        for (int g = 0; g < 4; ++g)
          gvv[r * 4 + g] = gp[(long)r * 4608 + g * 1150];
    }

    if (t > 0) {
      if (w == 0) {
        const unsigned tt = (unsigned)t;
        unsigned f1 = (s1 == us) ? tt :
            __hip_atomic_load(flags + (s1 << 5), __ATOMIC_RELAXED, __HIP_MEMORY_SCOPE_AGENT);
        unsigned f2 = (s2 == us) ? tt :
            __hip_atomic_load(flags + (s2 << 5), __ATOMIC_RELAXED, __HIP_MEMORY_SCOPE_AGENT);
        unsigned long long p1 = __ballot(f1 >= tt);
        unsigned long long p2 = __ballot(f2 >= tt);
        while ((p1 & p2) != ~0ull) {
          __builtin_amdgcn_s_sleep(2);
          if (!((p1 >> l) & 1))
            f1 = __hip_atomic_load(flags + (s1 << 5), __ATOMIC_RELAXED, __HIP_MEMORY_SCOPE_AGENT);
          if (!((p2 >> l) & 1))
            f2 = __hip_atomic_load(flags + (s2 << 5), __ATOMIC_RELAXED, __HIP_MEMORY_SCOPE_AGENT);
          p1 = __ballot(f1 >= tt);
          p2 = __ballot(f2 >= tt);
        }
      }
      __syncthreads();
      asm volatile("" ::: "memory");
    }

    const ushort_t* hp = hs + (long)t * 73728 + (long)(w * 16 + lrow) * 1152 + lk;
    f32x4 a0 = {}, a1 = {}, a2 = {}, a3 = {};

    bf16x8 A0[9], A1[9];
    auto ldg = [&](bf16x8* buf, int g) {
#pragma unroll
      for (int i = 0; i < 9; ++i) {
        int kc = start + g * 9 + i; if (kc >= 36) kc -= 36;
        buf[i] = *(const bf16x8*)(hp + kc * 32);
      }
    };
    auto cons = [&](const bf16x8* buf, int g) {
#pragma unroll
      for (int i = 0; i < 9; ++i) {
        int kc = start + g * 9 + i; if (kc >= 36) kc -= 36;
        int pc8 = ((kc * 4 + hi) ^ x7) * 8;
        a0 = __builtin_amdgcn_mfma_f32_16x16x32_bf16(buf[i], *(const bf16x8*)(Bg0 + pc8), a0, 0, 0, 0);
        a1 = __builtin_amdgcn_mfma_f32_16x16x32_bf16(buf[i], *(const bf16x8*)(Bg1 + pc8), a1, 0, 0, 0);
        a2 = __builtin_amdgcn_mfma_f32_16x16x32_bf16(buf[i], *(const bf16x8*)(Bg2 + pc8), a2, 0, 0, 0);
        a3 = __builtin_amdgcn_mfma_f32_16x16x32_bf16(buf[i], *(const bf16x8*)(Bg3 + pc8), a3, 0, 0, 0);
      }
    };
    ldg(A0, 0); ldg(A1, 1);
    cons(A0, 0); ldg(A0, 2);
    cons(A1, 1); ldg(A1, 3);
    cons(A0, 2);
    cons(A1, 3);

    if (u < 1150) {
#pragma unroll
      for (int r = 0; r < 4; ++r) {
        float iv = a0[r] + b2f(gvv[r * 4 + 0]);
        float fv = a1[r] + b2f(gvv[r * 4 + 1]);
        float gg = a2[r] + b2f(gvv[r * 4 + 2]);
        float ov = a3[r] + b2f(gvv[r * 4 + 3]);
        float cn = sigm(fv) * cc[r] + sigm(iv) * tanhfast(gg);
        cc[r] = cn;
        float hv = sigm(ov) * tanhfast(cn);
        store_short_wt(hs + (long)(t + 1) * 73728 + (long)(row0 + r) * 1152 + u, f2b(hv));
      }
    }

    if (t != 99) {
      asm volatile("s_waitcnt vmcnt(0)" ::: "memory");
      __syncthreads();
      if (tid == 0) store_uint_wt(flags + (us << 5), (unsigned)(t + 1));
    }
  }
}

// =====================================================================
// Fused causal attention (r16-proven vectorized form)
// =====================================================================
__global__ __launch_bounds__(256) void attn_kernel(
    const ushort_t* __restrict__ hs2,  // base at hs[1]: [100][64][1152] bf16
    ushort_t* __restrict__ outp)       // [6400][1152] bf16
{
  __shared__ float sc[104];
  __shared__ float sinv;
  const int rowi = blockIdx.x;  // t*64 + b
  const int t = rowi >> 6, b = rowi & 63;
  const int tid = threadIdx.x;
  const int w = tid >> 6, l = tid & 63;

  const ushort_t* q = hs2 + (long)rowi * 1152;
  us8 q0 = *(const us8*)(q + l * 8);
  us8 q1 = *(const us8*)(q + (l + 64) * 8);
  us8 q2 = {};
  if (l < 16) q2 = *(const us8*)(q + (l + 128) * 8);

  for (int s = w; s <= t; s += 4) {
    const ushort_t* k = hs2 + (long)(s * 64 + b) * 1152;
    us8 k0 = *(const us8*)(k + l * 8);
    us8 k1 = *(const us8*)(k + (l + 64) * 8);
    float p = 0.f;
#pragma unroll
    for (int e = 0; e < 8; ++e)
      p += b2f(q0[e]) * b2f(k0[e]) + b2f(q1[e]) * b2f(k1[e]);
    if (l < 16) {
      us8 k2 = *(const us8*)(k + (l + 128) * 8);
#pragma unroll
      for (int e = 0; e < 8; ++e) p += b2f(q2[e]) * b2f(k2[e]);
    }
    for (int off = 32; off; off >>= 1) p += __shfl_down(p, off);
    if (l == 0) sc[s] = p;
  }
  __syncthreads();

  if (w == 0) {
    float m = -1e30f;
    for (int s = l; s <= t; s += 64) m = fmaxf(m, sc[s]);
    for (int off = 32; off; off >>= 1) m = fmaxf(m, __shfl_down(m, off));
    m = __shfl(m, 0);
    float sum = 0.f;
    for (int s = l; s <= t; s += 64) { float e = __expf(sc[s] - m); sc[s] = e; sum += e; }
    for (int off = 32; off; off >>= 1) sum += __shfl_down(sum, off);
    if (l == 0) sinv = 1.f / sum;
  }
  __syncthreads();

  if (tid < 144) {
    const float si = sinv;
    float acc[8] = {};
    const ushort_t* vbase = hs2 + (long)b * 1152 + tid * 8;
#pragma unroll 4
    for (int s = 0; s <= t; ++s) {
      us8 v = *(const us8*)(vbase + (long)s * 73728);
      float ps = sc[s];
#pragma unroll
      for (int e = 0; e < 8; ++e) acc[e] += ps * b2f(v[e]);
    }
    union { us8 v; ushort_t s[8]; } pk;
#pragma unroll
    for (int e = 0; e < 8; ++e) pk.s[e] = f2b(acc[e] * si);
    *(us8*)(outp + (long)rowi * 1152 + tid * 8) = pk.v;
  }
}

// ---------- f32 -> bf16 conversion helpers ----------
__global__ void embed_kernel(const int* __restrict__ in1, const int* __restrict__ in2,
                             const float* __restrict__ emb, ushort_t* __restrict__ x0)
{
  int rowi = blockIdx.x;
  int l = threadIdx.x;    // 64 threads
  long r1 = (long)in1[rowi] * 400, r2 = (long)in2[rowi] * 400;
  ushort_t* d = x0 + (long)rowi * 832;
  for (int c = l; c < 832; c += 64) {
    ushort_t v = 0;
    if (c < 800) v = f2b(c < 400 ? emb[r1 + c] : emb[r2 + c - 400]);
    d[c] = v;
  }
}

__global__ void pad_convert(const float* __restrict__ in, ushort_t* __restrict__ out,
                            int R, int Cin, int total, int Cp)
{
  int idx = blockIdx.x * 256 + threadIdx.x;
  if (idx >= total) return;
  int r = idx / Cp, c = idx - r * Cp;
  float v = (r < R && c < Cin) ? in[(long)r * Cin + c] : 0.f;
  out[idx] = f2b(v);
}

__global__ void init_state(const float* __restrict__ h_in,
                           ushort_t* __restrict__ hs, unsigned* __restrict__ flags)
{
  int idx = blockIdx.x * 256 + threadIdx.x;
  if (idx < 72 * 32) flags[idx] = 0u;
  if (idx < 64 * 1152) {
    int b = idx / 1152, c = idx - b * 1152;
    hs[idx] = (c < 1150) ? f2b(h_in[b * 1150 + c]) : (ushort_t)0;
  }
  if (idx < 100 * 128) {
    int t = idx >> 7, r = idx & 127, b = r >> 1, k = r & 1;
    hs[(long)(t + 1) * 73728 + b * 1152 + 1150 + k] = 0;
  }
}

// =====================================================================
extern "C" void kernel_launch(void* const* d_in, const int* in_sizes, int n_in,
                              void* d_out, int out_size, void* d_ws, size_t ws_size,
                              hipStream_t stream) {
  (void)in_sizes; (void)n_in; (void)out_size; (void)ws_size;
  const int* input  = (const int*)d_in[0];
  const int* input2 = (const int*)d_in[1];
  const float* h_in[3] = {(const float*)d_in[2], (const float*)d_in[4], (const float*)d_in[6]};
  const float* c_in[3] = {(const float*)d_in[3], (const float*)d_in[5], (const float*)d_in[7]};
  const float* emb_W = (const float*)d_in[8];
  const float* W_ih[3] = {(const float*)d_in[9],  (const float*)d_in[13], (const float*)d_in[17]};
  const float* W_hh[3] = {(const float*)d_in[10], (const float*)d_in[14], (const float*)d_in[18]};
  const float* b_ih[3] = {(const float*)d_in[11], (const float*)d_in[15], (const float*)d_in[19]};
  const float* b_hh[3] = {(const float*)d_in[12], (const float*)d_in[16], (const float*)d_in[20]};
  const float* dec_W = (const float*)d_in[21];
  const float* dec_b = (const float*)d_in[22];
  float* out = (float*)d_out;

  hipFuncSetAttribute((const void*)lstm_layer,
                      hipFuncAttributeMaxDynamicSharedMemorySize, 147456);

  // ---- workspace: decoder-phase buffers + flags ----
  char* base = (char*)d_ws;
  size_t off = 0;
  auto walloc = [&](size_t bytes) { char* r = base + off; off += (bytes + 255) & ~(size_t)255; return r; };
  ushort_t* decWp = (ushort_t*)walloc(33280ull * 1152 * 2);   // 76,677,120
  ushort_t* attnB = (ushort_t*)walloc(6400ull * 1152 * 2);    // 14,745,600
  unsigned* flags = (unsigned*)walloc(72 * 128 + 256);

  // ---- layer-phase scratch inside d_out (all dead before decoder GEMM) ----
  char* ob = (char*)d_out;
  ushort_t* G   = (ushort_t*)(ob + 0);            // 58,982,400
  ushort_t* x0  = (ushort_t*)(ob + 58982400);     // 10,649,600
  ushort_t* Wp  = (ushort_t*)(ob + 69632000);     // 10,616,832
  ushort_t* Whp = (ushort_t*)(ob + 80248832);     // 10,616,832
  ushort_t* hsA = (ushort_t*)(ob + 90865664);     // 14,893,056
  ushort_t* hsB = (ushort_t*)(ob + 105758720);    // -> end 120,651,776

  embed_kernel<<<6400, 64, 0, stream>>>(input, input2, emb_W, x0);

  ushort_t* hcur[3] = {hsA, hsB, hsA};
  const ushort_t* X = x0;
  int lda = 832, Kp = 832;
  for (int lyr = 0; lyr < 3; lyr++) {
    if (lyr == 0) {
      int tot = 4608 * 832;
      pad_convert<<<(tot + 255) / 256, 256, 0, stream>>>(W_ih[0], Wp, 4600, 800, tot, 832);
    } else {
      int tot = 4608 * 1152;
      pad_convert<<<(tot + 255) / 256, 256, 0, stream>>>(W_ih[lyr], Wp, 4600, 1150, tot, 1152);
    }
    {
      int tot = 4608 * 1152;
      pad_convert<<<(tot + 255) / 256, 256, 0, stream>>>(W_hh[lyr], Whp, 4600, 1150, tot, 1152);
    }
    gemm256<false><<<dim3(25, 18), 512, 0, stream>>>(X, Wp, (void*)G, b_ih[lyr], b_hh[lyr],
                                                     lda, Kp, 4608L, Kp, 4600);
    init_state<<<288, 256, 0, stream>>>(h_in[lyr], hcur[lyr], flags);
    lstm_layer<<<72, 256, 147456, stream>>>(hcur[lyr], G, Whp, c_in[lyr], flags);
    X = hcur[lyr] + 73728;
    lda = 1152; Kp = 1152;
  }

  attn_kernel<<<6400, 256, 0, stream>>>(hsA + 73728, attnB);

  {
    int tot = 33280 * 1152;
    pad_convert<<<(tot + 255) / 256, 256, 0, stream>>>(dec_W, decWp, 33278, 1150, tot, 1152);
  }

  gemm256<true><<<dim3(25, 130), 512, 0, stream>>>(attnB, decWp, (void*)out, dec_b, nullptr,
                                                   1152, 1152, 33278L, 1152, 33278);
}

// Round 18
// 3242.806 us; speedup vs baseline: 1.0275x; 1.0275x over previous
//
#include <hip/hip_runtime.h>
#include <stdint.h>

typedef unsigned short ushort_t;
typedef __bf16 bf16x8 __attribute__((ext_vector_type(8)));
typedef ushort_t us8 __attribute__((ext_vector_type(8)));
typedef float f32x4 __attribute__((ext_vector_type(4)));

// ---------- bf16 <-> f32 (bit ops) ----------
__device__ __forceinline__ float b2f(ushort_t u) {
  union { unsigned u; float f; } v; v.u = ((unsigned)u) << 16; return v.f;
}
__device__ __forceinline__ ushort_t f2b(float f) {
  union { float f; unsigned u; } v; v.f = f;
  unsigned r = (v.u + 0x7FFFu + ((v.u >> 16) & 1u)) >> 16;
  return (ushort_t)r;
}

// ---------- fast transcendentals ----------
__device__ __forceinline__ float sigm(float x)     { return 1.f / (1.f + __expf(-x)); }
__device__ __forceinline__ float tanhfast(float x) { return 1.f - 2.f / (1.f + __expf(2.f * x)); }

// ---------- device-coherent write-through stores ----------
__device__ __forceinline__ void store_short_wt(ushort_t* p, ushort_t v) {
  asm volatile("global_store_short %0, %1, off sc0 sc1"
               :: "v"(p), "v"((unsigned)v) : "memory");
}
__device__ __forceinline__ void store_uint_wt(unsigned* p, unsigned v) {
  asm volatile("global_store_dword %0, %1, off sc0 sc1"
               :: "v"(p), "v"(v) : "memory");
}

// ---------- global -> LDS direct load, 16B per lane ----------
__device__ __forceinline__ void gload_lds16(const void* g, void* lds) {
  auto l3 = reinterpret_cast<__attribute__((address_space(3))) unsigned*>(
      reinterpret_cast<uintptr_t>(lds));
  __builtin_amdgcn_global_load_lds(reinterpret_cast<const unsigned*>(g), l3, 16, 0, 0);
}

// raw barrier with compiler memory fences (no vmcnt(0) drain)
__device__ __forceinline__ void rbar() {
  asm volatile("" ::: "memory");
  __builtin_amdgcn_s_barrier();
  asm volatile("" ::: "memory");
}

// =====================================================================
// 256x256 pipelined GEMM (r15/r16-proven BEST): BK=64, double-buffered
// 128KB dynamic LDS, counted vmcnt(8) (tile t+1 in flight while computing
// t), raw barriers, T2 swizzle both-sides (colE ^= (row&7)<<3), setprio.
// 512 thr = 8 waves (2Mx4N), wave tile 128x64, acc[8][4].
// Requires: M%256==0, B rows padded to gridDim.y*256, Kpad%64==0, nt>=2.
// =====================================================================
template <bool F32OUT>
__global__ __launch_bounds__(512) void gemm256(
    const ushort_t* __restrict__ A, const ushort_t* __restrict__ B,
    void* __restrict__ Cv,
    const float* __restrict__ bias0, const float* __restrict__ bias1,
    int lda, int ldb, long ldc, int Kpad, int N)
{
  extern __shared__ ushort_t sh[];   // [2 buf][A 16384 | B 16384] ushorts = 131072 B
  const int tid = threadIdx.x;
  const int w = tid >> 6, l = tid & 63;
  const int wr = w >> 2, wc = w & 3;
  const int lrow = l & 15, hi = l >> 4;
  const int xsw = (lrow & 7) << 3;

  // bijective XCD swizzle
  unsigned nwg = gridDim.x * gridDim.y;
  unsigned wg = blockIdx.y * gridDim.x + blockIdx.x;
  {
    unsigned q = nwg >> 3, r = nwg & 7u;
    unsigned xcd = wg & 7u, idx = wg >> 3;
    wg = (xcd < r ? xcd * (q + 1) : r * (q + 1) + (xcd - r) * q) + idx;
  }
  const long m0 = (long)(wg % gridDim.x) * 256;
  const long n0 = (long)(wg / gridDim.x) * 256;

  // staging: per tensor 2048 chunks of 8 ushorts; thread does 4.
  // linear LDS dest; global source col inverse-swizzled (same involution).
  int crow[4], csrc[4];
#pragma unroll
  for (int j = 0; j < 4; ++j) {
    int c = tid + j * 512;
    crow[j] = c >> 3;
    csrc[j] = ((c & 7) * 8) ^ ((crow[j] & 7) << 3);
  }

  auto STAGE = [&](int buf, int t) {
    const long k0 = (long)t * 64;
    ushort_t* dstA = sh + buf * 32768;
    ushort_t* dstB = dstA + 16384;
#pragma unroll
    for (int j = 0; j < 4; ++j)
      gload_lds16(A + (m0 + crow[j]) * lda + k0 + csrc[j], dstA + (tid + j * 512) * 8);
#pragma unroll
    for (int j = 0; j < 4; ++j)
      gload_lds16(B + (n0 + crow[j]) * ldb + k0 + csrc[j], dstB + (tid + j * 512) * 8);
  };

  f32x4 acc[8][4] = {};
  const int nt = Kpad >> 6;

  STAGE(0, 0);
  STAGE(1, 1);
  asm volatile("s_waitcnt vmcnt(8)" ::: "memory");   // tile 0 landed (tile 1 flying)
  rbar();

  for (int t = 0; t < nt; ++t) {
    const ushort_t* As = sh + (t & 1) * 32768;
    const ushort_t* Bs = As + 16384;
#pragma unroll
    for (int kk = 0; kk < 2; ++kk) {
      bf16x8 af[8], bfr[4];
      const int co = (kk * 32 + hi * 8) ^ xsw;
#pragma unroll
      for (int mi = 0; mi < 8; ++mi)
        af[mi] = *(const bf16x8*)(As + (wr * 128 + mi * 16 + lrow) * 64 + co);
#pragma unroll
      for (int ni = 0; ni < 4; ++ni)
        bfr[ni] = *(const bf16x8*)(Bs + (wc * 64 + ni * 16 + lrow) * 64 + co);
      __builtin_amdgcn_s_setprio(1);
#pragma unroll
      for (int mi = 0; mi < 8; ++mi)
#pragma unroll
        for (int ni = 0; ni < 4; ++ni)
          acc[mi][ni] = __builtin_amdgcn_mfma_f32_16x16x32_bf16(af[mi], bfr[ni], acc[mi][ni], 0, 0, 0);
      __builtin_amdgcn_s_setprio(0);
    }
    if (t + 2 < nt) {
      rbar();                       // all waves done reading buf[t&1]
      STAGE(t & 1, t + 2);          // 8 loads into the freed buffer
      asm volatile("s_waitcnt vmcnt(8)" ::: "memory");  // tile t+1 landed
      rbar();
    } else if (t + 1 < nt) {
      rbar();
      asm volatile("s_waitcnt vmcnt(0)" ::: "memory");
      rbar();
    }
  }

  // epilogue (r12-proven layout): lane -> col = lrow, rows = hi*4 + r
  const int rbase = hi * 4;
#pragma unroll
  for (int ni = 0; ni < 4; ni++) {
    int gcol = (int)n0 + wc * 64 + ni * 16 + lrow;
    if (gcol < N) {
      float badd = 0.f;
      if (bias0) badd += bias0[gcol];
      if (bias1) badd += bias1[gcol];
#pragma unroll
      for (int mi = 0; mi < 8; mi++) {
#pragma unroll
        for (int r = 0; r < 4; r++) {
          long grow = m0 + wr * 128 + mi * 16 + rbase + r;
          float v = acc[mi][ni][r] + badd;
          if (F32OUT) ((float*)Cv)[grow * ldc + gcol] = v;
          else        ((ushort_t*)Cv)[grow * ldc + gcol] = f2b(v);
        }
      }
    }
  }
}

// =====================================================================
// Persistent LSTM layer (r16-proven: flags + deep h-load pipeline,
// s_sleep(2) backoff)
// =====================================================================
__global__ __launch_bounds__(256) void lstm_layer(
    ushort_t* __restrict__ hs,        // [101][64][1152] bf16
    const ushort_t* __restrict__ G,   // [6400][4608] bf16
    const ushort_t* __restrict__ Whh, // padded [4608][1152] bf16
    const float* __restrict__ c_in,   // [64][1150] f32
    unsigned* __restrict__ flags)     // 72 lines of 128B
{
  extern __shared__ ushort_t Bsh[];
  const int tid = threadIdx.x;
  const int w = tid >> 6, l = tid & 63;
  const int us = blockIdx.x;
  const int lrow = l & 15, hi = l >> 4, lk = hi * 8;
  const int u = us * 16 + lrow;
  const int usafe = (u < 1150) ? u : 0;
  const int row0 = w * 16 + hi * 4;
  const int x7 = lrow & 7;
  const int start = us >> 1;

  for (int ci = tid; ci < 9216; ci += 256) {
    int gate = ci / 2304;
    int rem  = ci - gate * 2304;
    int row  = rem / 144;
    int c    = rem - row * 144;
    bf16x8 v = *(const bf16x8*)(Whh + ((long)(gate * 1150 + us * 16 + row)) * 1152 + c * 8);
    *(bf16x8*)(Bsh + (((gate * 16 + row) * 144) + (c ^ (row & 7))) * 8) = v;
  }
  const ushort_t* Bg0 = Bsh + ((0 * 16 + lrow) * 144) * 8;
  const ushort_t* Bg1 = Bsh + ((1 * 16 + lrow) * 144) * 8;
  const ushort_t* Bg2 = Bsh + ((2 * 16 + lrow) * 144) * 8;
  const ushort_t* Bg3 = Bsh + ((3 * 16 + lrow) * 144) * 8;

  f32x4 cc = {};
  if (u < 1150) {
#pragma unroll
    for (int r = 0; r < 4; ++r) cc[r] = c_in[(row0 + r) * 1150 + u];
  }
  __syncthreads();

  const int s1 = l, s2 = 64 + (l & 7);

  for (int t = 0; t < 100; ++t) {
    ushort_t gvv[16];
    {
      const ushort_t* gp = G + ((long)t * 64 + row0) * 4608 + usafe;
#pragma unroll
      for (int r = 0; r < 4; ++r)
#pragma unroll
        for (int g = 0; g < 4; ++g)
          gvv[r * 4 + g] = gp[(long)r * 4608 + g * 1150];
    }

    if (t > 0) {
      if (w == 0) {
        const unsigned tt = (unsigned)t;
        unsigned f1 = (s1 == us) ? tt :
            __hip_atomic_load(flags + (s1 << 5), __ATOMIC_RELAXED, __HIP_MEMORY_SCOPE_AGENT);
        unsigned f2 = (s2 == us) ? tt :
            __hip_atomic_load(flags + (s2 << 5), __ATOMIC_RELAXED, __HIP_MEMORY_SCOPE_AGENT);
        unsigned long long p1 = __ballot(f1 >= tt);
        unsigned long long p2 = __ballot(f2 >= tt);
        while ((p1 & p2) != ~0ull) {
          __builtin_amdgcn_s_sleep(2);
          if (!((p1 >> l) & 1))
            f1 = __hip_atomic_load(flags + (s1 << 5), __ATOMIC_RELAXED, __HIP_MEMORY_SCOPE_AGENT);
          if (!((p2 >> l) & 1))
            f2 = __hip_atomic_load(flags + (s2 << 5), __ATOMIC_RELAXED, __HIP_MEMORY_SCOPE_AGENT);
          p1 = __ballot(f1 >= tt);
          p2 = __ballot(f2 >= tt);
        }
      }
      __syncthreads();
      asm volatile("" ::: "memory");
    }

    const ushort_t* hp = hs + (long)t * 73728 + (long)(w * 16 + lrow) * 1152 + lk;
    f32x4 a0 = {}, a1 = {}, a2 = {}, a3 = {};

    bf16x8 A0[9], A1[9];
    auto ldg = [&](bf16x8* buf, int g) {
#pragma unroll
      for (int i = 0; i < 9; ++i) {
        int kc = start + g * 9 + i; if (kc >= 36) kc -= 36;
        buf[i] = *(const bf16x8*)(hp + kc * 32);
      }
    };
    auto cons = [&](const bf16x8* buf, int g) {
#pragma unroll
      for (int i = 0; i < 9; ++i) {
        int kc = start + g * 9 + i; if (kc >= 36) kc -= 36;
        int pc8 = ((kc * 4 + hi) ^ x7) * 8;
        a0 = __builtin_amdgcn_mfma_f32_16x16x32_bf16(buf[i], *(const bf16x8*)(Bg0 + pc8), a0, 0, 0, 0);
        a1 = __builtin_amdgcn_mfma_f32_16x16x32_bf16(buf[i], *(const bf16x8*)(Bg1 + pc8), a1, 0, 0, 0);
        a2 = __builtin_amdgcn_mfma_f32_16x16x32_bf16(buf[i], *(const bf16x8*)(Bg2 + pc8), a2, 0, 0, 0);
        a3 = __builtin_amdgcn_mfma_f32_16x16x32_bf16(buf[i], *(const bf16x8*)(Bg3 + pc8), a3, 0, 0, 0);
      }
    };
    ldg(A0, 0); ldg(A1, 1);
    cons(A0, 0); ldg(A0, 2);
    cons(A1, 1); ldg(A1, 3);
    cons(A0, 2);
    cons(A1, 3);

    if (u < 1150) {
#pragma unroll
      for (int r = 0; r < 4; ++r) {
        float iv = a0[r] + b2f(gvv[r * 4 + 0]);
        float fv = a1[r] + b2f(gvv[r * 4 + 1]);
        float gg = a2[r] + b2f(gvv[r * 4 + 2]);
        float ov = a3[r] + b2f(gvv[r * 4 + 3]);
        float cn = sigm(fv) * cc[r] + sigm(iv) * tanhfast(gg);
        cc[r] = cn;
        float hv = sigm(ov) * tanhfast(cn);
        store_short_wt(hs + (long)(t + 1) * 73728 + (long)(row0 + r) * 1152 + u, f2b(hv));
      }
    }

    if (t != 99) {
      asm volatile("s_waitcnt vmcnt(0)" ::: "memory");
      __syncthreads();
      if (tid == 0) store_uint_wt(flags + (us << 5), (unsigned)(t + 1));
    }
  }
}

// =====================================================================
// Fused causal attention (r16-proven vectorized form)
// =====================================================================
__global__ __launch_bounds__(256) void attn_kernel(
    const ushort_t* __restrict__ hs2,  // base at hs[1]: [100][64][1152] bf16
    ushort_t* __restrict__ outp)       // [6400][1152] bf16
{
  __shared__ float sc[104];
  __shared__ float sinv;
  const int rowi = blockIdx.x;  // t*64 + b
  const int t = rowi >> 6, b = rowi & 63;
  const int tid = threadIdx.x;
  const int w = tid >> 6, l = tid & 63;

  const ushort_t* q = hs2 + (long)rowi * 1152;
  us8 q0 = *(const us8*)(q + l * 8);
  us8 q1 = *(const us8*)(q + (l + 64) * 8);
  us8 q2 = {};
  if (l < 16) q2 = *(const us8*)(q + (l + 128) * 8);

  for (int s = w; s <= t; s += 4) {
    const ushort_t* k = hs2 + (long)(s * 64 + b) * 1152;
    us8 k0 = *(const us8*)(k + l * 8);
    us8 k1 = *(const us8*)(k + (l + 64) * 8);
    float p = 0.f;
#pragma unroll
    for (int e = 0; e < 8; ++e)
      p += b2f(q0[e]) * b2f(k0[e]) + b2f(q1[e]) * b2f(k1[e]);
    if (l < 16) {
      us8 k2 = *(const us8*)(k + (l + 128) * 8);
#pragma unroll
      for (int e = 0; e < 8; ++e) p += b2f(q2[e]) * b2f(k2[e]);
    }
    for (int off = 32; off; off >>= 1) p += __shfl_down(p, off);
    if (l == 0) sc[s] = p;
  }
  __syncthreads();

  if (w == 0) {
    float m = -1e30f;
    for (int s = l; s <= t; s += 64) m = fmaxf(m, sc[s]);
    for (int off = 32; off; off >>= 1) m = fmaxf(m, __shfl_down(m, off));
    m = __shfl(m, 0);
    float sum = 0.f;
    for (int s = l; s <= t; s += 64) { float e = __expf(sc[s] - m); sc[s] = e; sum += e; }
    for (int off = 32; off; off >>= 1) sum += __shfl_down(sum, off);
    if (l == 0) sinv = 1.f / sum;
  }
  __syncthreads();

  if (tid < 144) {
    const float si = sinv;
    float acc[8] = {};
    const ushort_t* vbase = hs2 + (long)b * 1152 + tid * 8;
#pragma unroll 4
    for (int s = 0; s <= t; ++s) {
      us8 v = *(const us8*)(vbase + (long)s * 73728);
      float ps = sc[s];
#pragma unroll
      for (int e = 0; e < 8; ++e) acc[e] += ps * b2f(v[e]);
    }
    union { us8 v; ushort_t s[8]; } pk;
#pragma unroll
    for (int e = 0; e < 8; ++e) pk.s[e] = f2b(acc[e] * si);
    *(us8*)(outp + (long)rowi * 1152 + tid * 8) = pk.v;
  }
}

// ---------- f32 -> bf16 conversion helpers ----------
__global__ void embed_kernel(const int* __restrict__ in1, const int* __restrict__ in2,
                             const float* __restrict__ emb, ushort_t* __restrict__ x0)
{
  int rowi = blockIdx.x;
  int l = threadIdx.x;    // 64 threads
  long r1 = (long)in1[rowi] * 400, r2 = (long)in2[rowi] * 400;
  ushort_t* d = x0 + (long)rowi * 832;
  for (int c = l; c < 832; c += 64) {
    ushort_t v = 0;
    if (c < 800) v = f2b(c < 400 ? emb[r1 + c] : emb[r2 + c - 400]);
    d[c] = v;
  }
}

__global__ void pad_convert(const float* __restrict__ in, ushort_t* __restrict__ out,
                            int R, int Cin, int total, int Cp)
{
  int idx = blockIdx.x * 256 + threadIdx.x;
  if (idx >= total) return;
  int r = idx / Cp, c = idx - r * Cp;
  float v = (r < R && c < Cin) ? in[(long)r * Cin + c] : 0.f;
  out[idx] = f2b(v);
}

__global__ void init_state(const float* __restrict__ h_in,
                           ushort_t* __restrict__ hs, unsigned* __restrict__ flags)
{
  int idx = blockIdx.x * 256 + threadIdx.x;
  if (idx < 72 * 32) flags[idx] = 0u;
  if (idx < 64 * 1152) {
    int b = idx / 1152, c = idx - b * 1152;
    hs[idx] = (c < 1150) ? f2b(h_in[b * 1150 + c]) : (ushort_t)0;
  }
  if (idx < 100 * 128) {
    int t = idx >> 7, r = idx & 127, b = r >> 1, k = r & 1;
    hs[(long)(t + 1) * 73728 + b * 1152 + 1150 + k] = 0;
  }
}

// =====================================================================
extern "C" void kernel_launch(void* const* d_in, const int* in_sizes, int n_in,
                              void* d_out, int out_size, void* d_ws, size_t ws_size,
                              hipStream_t stream) {
  (void)in_sizes; (void)n_in; (void)out_size; (void)ws_size;
  const int* input  = (const int*)d_in[0];
  const int* input2 = (const int*)d_in[1];
  const float* h_in[3] = {(const float*)d_in[2], (const float*)d_in[4], (const float*)d_in[6]};
  const float* c_in[3] = {(const float*)d_in[3], (const float*)d_in[5], (const float*)d_in[7]};
  const float* emb_W = (const float*)d_in[8];
  const float* W_ih[3] = {(const float*)d_in[9],  (const float*)d_in[13], (const float*)d_in[17]};
  const float* W_hh[3] = {(const float*)d_in[10], (const float*)d_in[14], (const float*)d_in[18]};
  const float* b_ih[3] = {(const float*)d_in[11], (const float*)d_in[15], (const float*)d_in[19]};
  const float* b_hh[3] = {(const float*)d_in[12], (const float*)d_in[16], (const float*)d_in[20]};
  const float* dec_W = (const float*)d_in[21];
  const float* dec_b = (const float*)d_in[22];
  float* out = (float*)d_out;

  hipFuncSetAttribute((const void*)lstm_layer,
                      hipFuncAttributeMaxDynamicSharedMemorySize, 147456);
  hipFuncSetAttribute(reinterpret_cast<const void*>(gemm256<false>),
                      hipFuncAttributeMaxDynamicSharedMemorySize, 131072);
  hipFuncSetAttribute(reinterpret_cast<const void*>(gemm256<true>),
                      hipFuncAttributeMaxDynamicSharedMemorySize, 131072);

  // ---- workspace: decoder-phase buffers + flags ----
  char* base = (char*)d_ws;
  size_t off = 0;
  auto walloc = [&](size_t bytes) { char* r = base + off; off += (bytes + 255) & ~(size_t)255; return r; };
  ushort_t* decWp = (ushort_t*)walloc(33280ull * 1152 * 2);   // 76,677,120
  ushort_t* attnB = (ushort_t*)walloc(6400ull * 1152 * 2);    // 14,745,600
  unsigned* flags = (unsigned*)walloc(72 * 128 + 256);

  // ---- layer-phase scratch inside d_out (all dead before decoder GEMM) ----
  char* ob = (char*)d_out;
  ushort_t* G   = (ushort_t*)(ob + 0);            // 58,982,400
  ushort_t* x0  = (ushort_t*)(ob + 58982400);     // 10,649,600
  ushort_t* Wp  = (ushort_t*)(ob + 69632000);     // 10,616,832
  ushort_t* Whp = (ushort_t*)(ob + 80248832);     // 10,616,832
  ushort_t* hsA = (ushort_t*)(ob + 90865664);     // 14,893,056
  ushort_t* hsB = (ushort_t*)(ob + 105758720);    // -> end 120,651,776

  embed_kernel<<<6400, 64, 0, stream>>>(input, input2, emb_W, x0);

  ushort_t* hcur[3] = {hsA, hsB, hsA};
  const ushort_t* X = x0;
  int lda = 832, Kp = 832;
  for (int lyr = 0; lyr < 3; lyr++) {
    if (lyr == 0) {
      int tot = 4608 * 832;
      pad_convert<<<(tot + 255) / 256, 256, 0, stream>>>(W_ih[0], Wp, 4600, 800, tot, 832);
    } else {
      int tot = 4608 * 1152;
      pad_convert<<<(tot + 255) / 256, 256, 0, stream>>>(W_ih[lyr], Wp, 4600, 1150, tot, 1152);
    }
    {
      int tot = 4608 * 1152;
      pad_convert<<<(tot + 255) / 256, 256, 0, stream>>>(W_hh[lyr], Whp, 4600, 1150, tot, 1152);
    }
    gemm256<false><<<dim3(25, 18), 512, 131072, stream>>>(X, Wp, (void*)G, b_ih[lyr], b_hh[lyr],
                                                          lda, Kp, 4608L, Kp, 4600);
    init_state<<<288, 256, 0, stream>>>(h_in[lyr], hcur[lyr], flags);
    lstm_layer<<<72, 256, 147456, stream>>>(hcur[lyr], G, Whp, c_in[lyr], flags);
    X = hcur[lyr] + 73728;
    lda = 1152; Kp = 1152;
  }

  attn_kernel<<<6400, 256, 0, stream>>>(hsA + 73728, attnB);

  {
    int tot = 33280 * 1152;
    pad_convert<<<(tot + 255) / 256, 256, 0, stream>>>(dec_W, decWp, 33278, 1150, tot, 1152);
  }

  gemm256<true><<<dim3(25, 130), 512, 131072, stream>>>(attnB, decWp, (void*)out, dec_b, nullptr,
                                                        1152, 1152, 33278L, 1152, 33278);
}